// Round 9
// baseline (198.199 us; speedup 1.0000x reference)
//
#include <hip/hip_runtime.h>

// out = x * diag (broadcast over last axis). x: 32768 x 4096 f32, diag: 4096 f32.
// R9: R8 chunked kernel + CLUSTERED loads (4 loads issued back-to-back, then
// 4 mul+stores) within the contiguous 16KB window. Tests whether R5's batch
// regression was the 8MB address scatter (fixed here) or batching itself.

#define CH4 1024   // 4096 channels / 4 floats per float4

typedef float f32x4 __attribute__((ext_vector_type(4)));

// Chunked kernel: requires chunk % CH4 == 0, n4 % chunk == 0, (chunk/256)%4==0.
__global__ __launch_bounds__(256)
void DiagonalLinear_chunked(const f32x4* __restrict__ x,
                            const f32x4* __restrict__ diag,
                            f32x4* __restrict__ out,
                            unsigned int chunk) {
    const unsigned int tid  = threadIdx.x;
    const unsigned int base = blockIdx.x * chunk + tid;
    const unsigned int iters = chunk >> 8;   // / 256

    // chunk multiple of 1024 -> each thread cycles through 4 channel groups.
    const f32x4 d0 = diag[tid];
    const f32x4 d1 = diag[tid + 256];
    const f32x4 d2 = diag[tid + 512];
    const f32x4 d3 = diag[tid + 768];

    unsigned int idx = base;
    for (unsigned int k = 0; k < iters; k += 4, idx += 1024) {
        // 4 independent loads (64B/lane in flight, all within 16KB window)
        f32x4 a = __builtin_nontemporal_load(&x[idx]);
        f32x4 b = __builtin_nontemporal_load(&x[idx + 256]);
        f32x4 c = __builtin_nontemporal_load(&x[idx + 512]);
        f32x4 d = __builtin_nontemporal_load(&x[idx + 768]);
        // then 4 mul+stores
        __builtin_nontemporal_store(a * d0, &out[idx]);
        __builtin_nontemporal_store(b * d1, &out[idx + 256]);
        __builtin_nontemporal_store(c * d2, &out[idx + 512]);
        __builtin_nontemporal_store(d * d3, &out[idx + 768]);
    }
}

// Fallback: grid-stride kernel (general shapes).
template <bool HOIST>
__global__ __launch_bounds__(256)
void DiagonalLinear_gs(const f32x4* __restrict__ x,
                       const f32x4* __restrict__ diag,
                       f32x4* __restrict__ out,
                       unsigned int n4) {
    const unsigned int stride = gridDim.x * blockDim.x;
    unsigned int i = blockIdx.x * blockDim.x + threadIdx.x;
    f32x4 dv;
    if (HOIST) dv = diag[i & (CH4 - 1)];
    for (; i < n4; i += stride) {
        f32x4 xv = __builtin_nontemporal_load(&x[i]);
        f32x4 dvv = HOIST ? dv : diag[i & (CH4 - 1)];
        __builtin_nontemporal_store(xv * dvv, &out[i]);
    }
}

extern "C" void kernel_launch(void* const* d_in, const int* in_sizes, int n_in,
                              void* d_out, int out_size, void* d_ws, size_t ws_size,
                              hipStream_t stream) {
    const float* x    = (const float*)d_in[0];
    const float* diag = (const float*)d_in[1];
    float* out        = (float*)d_out;

    const long long n  = (long long)in_sizes[0];   // 32768*4096
    const unsigned int n4 = (unsigned int)(n / 4); // 2^25, fits u32

    const int block = 256;
    const int grid  = 2048;
    const unsigned int chunk = n4 / grid;          // 16384 float4 per block

    if ((long long)grid * chunk == (long long)n4 &&
        (chunk & (CH4 - 1)) == 0 && ((chunk >> 8) & 3) == 0) {
        DiagonalLinear_chunked<<<grid, block, 0, stream>>>(
            (const f32x4*)x, (const f32x4*)diag, (f32x4*)out, chunk);
    } else {
        long long want = ((long long)n4 + block - 1) / block;
        int g = (int)(want < 2048 ? want : 2048);
        const unsigned int stride = (unsigned int)g * block;
        if ((stride & (CH4 - 1)) == 0) {
            DiagonalLinear_gs<true><<<g, block, 0, stream>>>(
                (const f32x4*)x, (const f32x4*)diag, (f32x4*)out, n4);
        } else {
            DiagonalLinear_gs<false><<<g, block, 0, stream>>>(
                (const f32x4*)x, (const f32x4*)diag, (f32x4*)out, n4);
        }
    }
}

// Round 10
// 192.451 us; speedup vs baseline: 1.0299x; 1.0299x over previous
//
#include <hip/hip_runtime.h>

// out = x * diag (broadcast over last axis). x: 32768 x 4096 f32, diag: 4096 f32.
// R10: 1024-thread blocks, 512 blocks (2/CU, 32 waves/CU = full occupancy).
// Each block-wide access = 16KB aligned contiguous (DRAM-page-sized burst);
// 512 streams instead of 2048. tid spans exactly CH4 -> one dv per thread.
// Keeps R6-R8 wins: nt load+store, block-contiguous chunks.

#define CH4 1024   // 4096 channels / 4 floats per float4

typedef float f32x4 __attribute__((ext_vector_type(4)));

// Wide kernel: blockDim.x == 1024 == CH4; requires chunk % 1024 == 0.
__global__ __launch_bounds__(1024)
void DiagonalLinear_wide(const f32x4* __restrict__ x,
                         const f32x4* __restrict__ diag,
                         f32x4* __restrict__ out,
                         unsigned int chunk) {
    const unsigned int tid = threadIdx.x;       // 0..1023 == channel group
    const f32x4 dv = diag[tid];                 // one channel group per thread
    unsigned int idx = blockIdx.x * chunk + tid;
    const unsigned int end = blockIdx.x * chunk + chunk;
#pragma unroll 4
    for (; idx < end; idx += 1024) {
        f32x4 v = __builtin_nontemporal_load(&x[idx]);
        __builtin_nontemporal_store(v * dv, &out[idx]);
    }
}

// Fallback: R8 chunked kernel (256-thread blocks).
__global__ __launch_bounds__(256)
void DiagonalLinear_chunked(const f32x4* __restrict__ x,
                            const f32x4* __restrict__ diag,
                            f32x4* __restrict__ out,
                            unsigned int chunk) {
    const unsigned int tid  = threadIdx.x;
    const unsigned int iters = chunk >> 8;
    const f32x4 d0 = diag[tid];
    const f32x4 d1 = diag[tid + 256];
    const f32x4 d2 = diag[tid + 512];
    const f32x4 d3 = diag[tid + 768];
    unsigned int idx = blockIdx.x * chunk + tid;
    for (unsigned int k = 0; k < iters; k += 4, idx += 1024) {
        f32x4 a = __builtin_nontemporal_load(&x[idx]);
        __builtin_nontemporal_store(a * d0, &out[idx]);
        f32x4 b = __builtin_nontemporal_load(&x[idx + 256]);
        __builtin_nontemporal_store(b * d1, &out[idx + 256]);
        f32x4 c = __builtin_nontemporal_load(&x[idx + 512]);
        __builtin_nontemporal_store(c * d2, &out[idx + 512]);
        f32x4 d = __builtin_nontemporal_load(&x[idx + 768]);
        __builtin_nontemporal_store(d * d3, &out[idx + 768]);
    }
}

// General fallback: grid-stride.
template <bool HOIST>
__global__ __launch_bounds__(256)
void DiagonalLinear_gs(const f32x4* __restrict__ x,
                       const f32x4* __restrict__ diag,
                       f32x4* __restrict__ out,
                       unsigned int n4) {
    const unsigned int stride = gridDim.x * blockDim.x;
    unsigned int i = blockIdx.x * blockDim.x + threadIdx.x;
    f32x4 dv;
    if (HOIST) dv = diag[i & (CH4 - 1)];
    for (; i < n4; i += stride) {
        f32x4 xv = __builtin_nontemporal_load(&x[i]);
        f32x4 dvv = HOIST ? dv : diag[i & (CH4 - 1)];
        __builtin_nontemporal_store(xv * dvv, &out[i]);
    }
}

extern "C" void kernel_launch(void* const* d_in, const int* in_sizes, int n_in,
                              void* d_out, int out_size, void* d_ws, size_t ws_size,
                              hipStream_t stream) {
    const float* x    = (const float*)d_in[0];
    const float* diag = (const float*)d_in[1];
    float* out        = (float*)d_out;

    const long long n  = (long long)in_sizes[0];   // 32768*4096
    const unsigned int n4 = (unsigned int)(n / 4); // 2^25, fits u32

    // Wide path: 512 blocks x 1024 threads, chunk multiple of 1024.
    {
        const int grid = 512;
        const unsigned int chunk = n4 / grid;      // 65536 float4 per block
        if ((long long)grid * chunk == (long long)n4 && (chunk & (CH4 - 1)) == 0) {
            DiagonalLinear_wide<<<grid, 1024, 0, stream>>>(
                (const f32x4*)x, (const f32x4*)diag, (f32x4*)out, chunk);
            return;
        }
    }
    // Chunked path: 2048 blocks x 256 threads.
    {
        const int grid = 2048;
        const unsigned int chunk = n4 / grid;
        if ((long long)grid * chunk == (long long)n4 &&
            (chunk & (CH4 - 1)) == 0 && ((chunk >> 8) & 3) == 0) {
            DiagonalLinear_chunked<<<grid, 256, 0, stream>>>(
                (const f32x4*)x, (const f32x4*)diag, (f32x4*)out, chunk);
            return;
        }
    }
    // General path.
    const int block = 256;
    long long want = ((long long)n4 + block - 1) / block;
    int g = (int)(want < 2048 ? want : 2048);
    const unsigned int stride = (unsigned int)g * block;
    if ((stride & (CH4 - 1)) == 0) {
        DiagonalLinear_gs<true><<<g, block, 0, stream>>>(
            (const f32x4*)x, (const f32x4*)diag, (f32x4*)out, n4);
    } else {
        DiagonalLinear_gs<false><<<g, block, 0, stream>>>(
            (const f32x4*)x, (const f32x4*)diag, (f32x4*)out, n4);
    }
}